// Round 13
// baseline (307.543 us; speedup 1.0000x reference)
//
#include <hip/hip_runtime.h>
#include <hip/hip_fp16.h>

typedef _Float16 half8 __attribute__((ext_vector_type(8)));
typedef _Float16 half4v __attribute__((ext_vector_type(4)));
typedef float floatx4 __attribute__((ext_vector_type(4)));

// ---------------- async global->LDS (16B per lane) ----------------
__device__ __forceinline__ void load_lds16(const void* g, void* l) {
    __builtin_amdgcn_global_load_lds(
        (const __attribute__((address_space(1))) void*)g,
        (__attribute__((address_space(3))) void*)l,
        16, 0, 0);
}

// Stage one 128x64 fp16 half-tile (16 KiB) into LDS. LDS dest linear;
// SOURCE slot XOR-pre-swizzled (slot ^= row&7) -- Guideline 21.
__device__ __forceinline__ void stage_half(const _Float16* g, long ld, _Float16* dst) {
    const int t = threadIdx.x;  // 512 threads x 2 chunks x 16B
#pragma unroll
    for (int j = 0; j < 2; ++j) {
        const int c = j * 512 + t;             // 0..1023
        const int row = c >> 3;                // 0..127
        const int slot = (c & 7) ^ (row & 7);  // pre-swizzled source slot
        load_lds16(g + (long)row * ld + slot * 8, dst + c * 8);
    }
}

#define GEMM_PRELUDE                                                               \
    const int lane = threadIdx.x & 63;                                             \
    const int w    = threadIdx.x >> 6;                                             \
    const int wr   = w >> 2;                                                       \
    const int wc   = w & 3;                                                        \
    const int rsel = lane & 15, gsel = lane >> 4;                                  \
    const int NT = K >> 6;                                                         \
    (void)lane;
#define STAGE(BUF, KT)                                                             \
    stage_half(A + (KT) * 64, lda, lds + (BUF) * 32768);                           \
    stage_half(A + (long)128 * lda + (KT) * 64, lda, lds + (BUF) * 32768 + 8192);  \
    stage_half(B + (KT) * 64, ldb, lds + (BUF) * 32768 + 16384);                   \
    stage_half(B + (long)128 * ldb + (KT) * 64, ldb, lds + (BUF) * 32768 + 24576);
#define READ_A(dst, AH, MH)                                                        \
    _Pragma("unroll") for (int mi = 0; mi < 4; ++mi) {                             \
        const int r = ((MH) * 4 + mi) * 16 + rsel;                                 \
        dst[mi][0] = *(const half8*)&(AH)[r * 64 + ((gsel ^ (r & 7)) << 3)];       \
        dst[mi][1] = *(const half8*)&(AH)[r * 64 + (((4 + gsel) ^ (r & 7)) << 3)]; \
    }
#define READ_B(dst, BH, NH)                                                        \
    _Pragma("unroll") for (int ni = 0; ni < 2; ++ni) {                             \
        const int rn = (wc & 1) * 64 + ((NH) * 2 + ni) * 16 + rsel;                \
        dst[ni][0] = *(const half8*)&(BH)[rn * 64 + ((gsel ^ (rn & 7)) << 3)];     \
        dst[ni][1] = *(const half8*)&(BH)[rn * 64 + (((4 + gsel) ^ (rn & 7)) << 3)]; \
    }
#define MFMA_Q(MH, NH, A_, B_)                                                     \
    _Pragma("unroll") for (int mi = 0; mi < 4; ++mi)                               \
    _Pragma("unroll") for (int ni = 0; ni < 2; ++ni) {                             \
        acc[(MH) * 4 + mi][(NH) * 2 + ni] = __builtin_amdgcn_mfma_f32_16x16x32_f16( \
            A_[mi][0], B_[ni][0], acc[(MH) * 4 + mi][(NH) * 2 + ni], 0, 0, 0);     \
        acc[(MH) * 4 + mi][(NH) * 2 + ni] = __builtin_amdgcn_mfma_f32_16x16x32_f16( \
            A_[mi][1], B_[ni][1], acc[(MH) * 4 + mi][(NH) * 2 + ni], 0, 0, 0);     \
    }
#define SB0 __builtin_amdgcn_sched_barrier(0)

// ---------------- 256x256 gemm_bt core (R7-verified, 42%) ----------
__device__ __forceinline__ void gemm256_core(const _Float16* A, long lda,
                                             const _Float16* B, long ldb,
                                             int K, floatx4 acc[8][4],
                                             _Float16* lds) {
    GEMM_PRELUDE
    half8 a_lo[4][2], a_hi[4][2], b_lo[2][2], b_hi[2][2];
    STAGE(0, 0);
    asm volatile("s_waitcnt vmcnt(0)" ::: "memory");
    __builtin_amdgcn_s_barrier();
    SB0;
#pragma unroll 1
    for (int t = 0; t < NT; ++t) {
        const int buf = t & 1;
        if (t + 1 < NT) { STAGE(buf ^ 1, t + 1); }
        const _Float16* Ah = lds + buf * 32768 + wr * 8192;
        const _Float16* Bh = lds + buf * 32768 + 16384 + (wc >> 1) * 8192;
        READ_A(a_lo, Ah, 0);
        READ_B(b_lo, Bh, 0);
        SB0;
        READ_A(a_hi, Ah, 1);
        SB0;
        READ_B(b_hi, Bh, 1);
        asm volatile("s_waitcnt lgkmcnt(12)" ::: "memory");
        SB0;
        MFMA_Q(0, 0, a_lo, b_lo);
        asm volatile("s_waitcnt lgkmcnt(4)" ::: "memory");
        SB0;
        MFMA_Q(1, 0, a_hi, b_lo);
        asm volatile("s_waitcnt lgkmcnt(0)" ::: "memory");
        SB0;
        MFMA_Q(0, 1, a_lo, b_hi);
        MFMA_Q(1, 1, a_hi, b_hi);
        asm volatile("s_waitcnt vmcnt(0)" ::: "memory");
        __builtin_amdgcn_s_barrier();
        SB0;
    }
}

// ---------------- 8-phase core (m201 template, minimal pins) -- qkv only ----
// Quadrant phases, counted vmcnt(4) at P4/P8, setprio around MFMA clusters,
// SB0 only after counted waits (rule 18). Stage slots: race-free (each STG
// targets a slot whose last reads completed >=1 barrier-pair earlier).
// Tail: clamped redundant stages; trailing vmcnt(0)+barrier protects the
// epilogue's LDS reuse from in-flight redundant loads.
__device__ __forceinline__ void gemm256_core8(const _Float16* A, long lda,
                                              const _Float16* B, long ldb,
                                              int K, floatx4 acc[8][4],
                                              _Float16* lds) {
    const int lane = threadIdx.x & 63;
    const int w = threadIdx.x >> 6;
    const int wr = w >> 2, wc = w & 3;
    const int rsel = lane & 15, gsel = lane >> 4;
    const int NT = K >> 6, NI = NT >> 1;
    (void)lane;

#define ASL(BUF, H) (lds + (BUF) * 32768 + (H) * 8192)
#define BSL(BUF, H) (lds + (BUF) * 32768 + 16384 + (H) * 8192)
#define STG_A(BUF, H, KT) stage_half(A + (long)(H) * 128 * lda + (KT) * 64, lda, ASL(BUF, H))
#define STG_B(BUF, H, KT) stage_half(B + (long)(H) * 128 * ldb + (KT) * 64, ldb, BSL(BUF, H))
#define PH(MH, NH, A_, B_)                                         \
    __builtin_amdgcn_s_barrier();                                  \
    asm volatile("s_waitcnt lgkmcnt(0)" ::: "memory");             \
    __builtin_amdgcn_sched_barrier(0);                             \
    __builtin_amdgcn_s_setprio(1);                                 \
    MFMA_Q(MH, NH, A_, B_);                                        \
    __builtin_amdgcn_s_setprio(0);                                 \
    __builtin_amdgcn_s_barrier();

    half8 a_lo[4][2], a_hi[4][2], b_lo[2][2], b_hi[2][2];

    // prologue: tile0 fully staged (8 loads) + tile1 A-halves (4 loads)
    STG_A(0, 0, 0); STG_A(0, 1, 0); STG_B(0, 0, 0); STG_B(0, 1, 0);
    STG_A(1, 0, 1); STG_A(1, 1, 1);
    asm volatile("s_waitcnt vmcnt(4)" ::: "memory");
    __builtin_amdgcn_s_barrier();

#pragma unroll 1
    for (int i = 0; i < NI; ++i) {
        const int t1 = 2 * i + 1;
        const int s2 = (2 * i + 2 < NT) ? 2 * i + 2 : NT - 1;  // tail clamp
        const int s3 = (2 * i + 3 < NT) ? 2 * i + 3 : NT - 1;  // never consumed
        const _Float16* Ah0 = ASL(0, wr);
        const _Float16* Bh0 = BSL(0, wc >> 1);
        const _Float16* Ah1 = ASL(1, wr);
        const _Float16* Bh1 = BSL(1, wc >> 1);
        // ---- tile 2i (buf0): quadrant phases
        READ_A(a_lo, Ah0, 0); READ_B(b_lo, Bh0, 0); STG_B(1, 0, t1);
        asm volatile("s_waitcnt lgkmcnt(8)" ::: "memory");
        PH(0, 0, a_lo, b_lo);
        READ_A(a_hi, Ah0, 1); STG_B(1, 1, t1);
        PH(1, 0, a_hi, b_lo);
        READ_B(b_hi, Bh0, 1); STG_A(0, 0, s2);
        PH(0, 1, a_lo, b_hi);
        STG_A(0, 1, s2);
        asm volatile("s_waitcnt vmcnt(4)" ::: "memory");  // buf1/tile t1 landed
        PH(1, 1, a_hi, b_hi);
        // ---- tile 2i+1 (buf1)
        READ_A(a_lo, Ah1, 0); READ_B(b_lo, Bh1, 0); STG_B(0, 0, s2);
        asm volatile("s_waitcnt lgkmcnt(8)" ::: "memory");
        PH(0, 0, a_lo, b_lo);
        READ_A(a_hi, Ah1, 1); STG_B(0, 1, s2);
        PH(1, 0, a_hi, b_lo);
        READ_B(b_hi, Bh1, 1); STG_A(1, 0, s3);
        PH(0, 1, a_lo, b_hi);
        STG_A(1, 1, s3);
        asm volatile("s_waitcnt vmcnt(4)" ::: "memory");  // buf0/tile s2 landed
        PH(1, 1, a_hi, b_hi);
    }
    asm volatile("s_waitcnt vmcnt(0)" ::: "memory");  // drain redundant stages
    __builtin_amdgcn_s_barrier();
#undef ASL
#undef BSL
#undef STG_A
#undef STG_B
#undef PH
}

// ---------------- pv variant: per-row fp16 A-scaling from LDS table --------
__device__ __forceinline__ void gemm256_core_pv(const _Float16* A, long lda,
                                                const _Float16* B, long ldb,
                                                int K, floatx4 acc[8][4],
                                                _Float16* lds, const float* scl) {
    GEMM_PRELUDE
    half8 a_lo[4][2], a_hi[4][2], b_lo[2][2], b_hi[2][2];
    STAGE(0, 0);
    asm volatile("s_waitcnt vmcnt(0)" ::: "memory");
    __builtin_amdgcn_s_barrier();
    SB0;
#pragma unroll 1
    for (int t = 0; t < NT; ++t) {
        const int buf = t & 1;
        if (t + 1 < NT) { STAGE(buf ^ 1, t + 1); }
        const _Float16* Ah = lds + buf * 32768 + wr * 8192;
        const _Float16* Bh = lds + buf * 32768 + 16384 + (wc >> 1) * 8192;
        const float* srow = scl + (t >> 2) * 256 + wr * 128 + rsel;
        float s_lo[4], s_hi[4];
#pragma unroll
        for (int mi = 0; mi < 4; ++mi) s_lo[mi] = srow[mi * 16];
#pragma unroll
        for (int mi = 0; mi < 4; ++mi) s_hi[mi] = srow[64 + mi * 16];
        SB0;
        READ_A(a_lo, Ah, 0);
        READ_B(b_lo, Bh, 0);
        SB0;
        READ_A(a_hi, Ah, 1);
        SB0;
        READ_B(b_hi, Bh, 1);
        asm volatile("s_waitcnt lgkmcnt(12)" ::: "memory");
        SB0;
#pragma unroll
        for (int mi = 0; mi < 4; ++mi) {
            const _Float16 h = (_Float16)s_lo[mi];
            a_lo[mi][0] = a_lo[mi][0] * h;
            a_lo[mi][1] = a_lo[mi][1] * h;
        }
        MFMA_Q(0, 0, a_lo, b_lo);
        asm volatile("s_waitcnt lgkmcnt(4)" ::: "memory");
        SB0;
#pragma unroll
        for (int mi = 0; mi < 4; ++mi) {
            const _Float16 h = (_Float16)s_hi[mi];
            a_hi[mi][0] = a_hi[mi][0] * h;
            a_hi[mi][1] = a_hi[mi][1] * h;
        }
        MFMA_Q(1, 0, a_hi, b_lo);
        asm volatile("s_waitcnt lgkmcnt(0)" ::: "memory");
        SB0;
        MFMA_Q(0, 1, a_lo, b_hi);
        MFMA_Q(1, 1, a_hi, b_hi);
        asm volatile("s_waitcnt vmcnt(0)" ::: "memory");
        __builtin_amdgcn_s_barrier();
        SB0;
    }
}

__device__ __forceinline__ void zero_acc8(floatx4 acc[8][4]) {
    const floatx4 z = {0.f, 0.f, 0.f, 0.f};
#pragma unroll
    for (int m = 0; m < 8; ++m)
#pragma unroll
        for (int n = 0; n < 4; ++n) acc[m][n] = z;
}

// ---------------- kernels ----------------

// merged prep: blocks [0,16384) build X fp16; [16384,20480) convert weights.
__global__ __launch_bounds__(256) void prep_kernel(const float* e1, const float* e2,
                                                   const float* e3, const float* Wq,
                                                   const float* Wk, const float* Wv,
                                                   const float* Wf, _Float16* X,
                                                   _Float16* Wdst) {
    const int bid = blockIdx.x;
    if (bid < 16384) {
        long i = ((long)bid * 256 + threadIdx.x) * 4;
        int m = (int)(i >> 10);
        int c = (int)(i & 1023);
        const float* src;
        if (c < 256)      src = e1 + (long)m * 256 + c;
        else if (c < 512) src = e2 + (long)m * 256 + (c - 256);
        else              src = e3 + (long)m * 512 + (c - 512);
        float4 f = *(const float4*)src;
        half4v h;
        h[0] = (_Float16)f.x; h[1] = (_Float16)f.y;
        h[2] = (_Float16)f.z; h[3] = (_Float16)f.w;
        *(half4v*)&X[i] = h;
    } else {
        long i = ((long)(bid - 16384) * 256 + threadIdx.x) * 4;
        int which = (int)(i >> 20);
        long off = i & 1048575;
        const float* w = which == 0 ? Wq : which == 1 ? Wk : which == 2 ? Wv : Wf;
        float4 f = *(const float4*)(w + off);
        half4v h;
        h[0] = (_Float16)f.x; h[1] = (_Float16)f.y;
        h[2] = (_Float16)f.z; h[3] = (_Float16)f.w;
        *(half4v*)&Wdst[i] = h;
    }
}

// QKV projection: z=0 -> q, z=1 -> k; z=2 -> vT via LDS transpose.
// Uses the 8-phase core (this round's experiment).
__global__ __launch_bounds__(512, 2) void qkv_kernel(const _Float16* X, const _Float16* W,
                                                     const float* bq, const float* bk,
                                                     const float* bv, _Float16* q,
                                                     _Float16* k, _Float16* vT) {
    extern __shared__ _Float16 lds[];
    const int m0 = blockIdx.x * 256;
    const int n0 = blockIdx.y * 256;
    const int z  = blockIdx.z;
    floatx4 acc[8][4];
    zero_acc8(acc);
    gemm256_core8(X + (long)m0 * 1024, 1024,
                  W + (long)z * 1048576 + (long)n0 * 1024, 1024, 1024, acc, lds);

    const float* bias = (z == 0) ? bq : (z == 1) ? bk : bv;
    const int lane = threadIdx.x & 63;
    const int w = threadIdx.x >> 6;
    const int wr = w >> 2, wc = w & 3;
    const int rsel = lane & 15, gsel = lane >> 4;

    if (z == 2) {
        const int rb = wr * 128 + gsel * 4;
        const int cb = wc * 64 + rsel;
#pragma unroll
        for (int mI = 0; mI < 8; ++mI) {
#pragma unroll
            for (int nI = 0; nI < 4; ++nI) {
                const int c = cb + nI * 16;
                const int r = rb + mI * 16;
                const float bb = bias[n0 + c];
                half4v vv;
#pragma unroll
                for (int j = 0; j < 4; ++j) vv[j] = (_Float16)(acc[mI][nI][j] + bb);
                *(half4v*)&lds[c * 256 + (r ^ ((c & 7) << 3))] = vv;
            }
        }
        __syncthreads();
#pragma unroll
        for (int it = 0; it < 16; ++it) {
            const int idx = it * 512 + threadIdx.x;  // 0..8191
            const int c = idx >> 5;
            const int mc = idx & 31;
            half8 v = *(const half8*)&lds[c * 256 + ((mc * 8) ^ ((c & 7) << 3))];
            *(half8*)&vT[(long)(n0 + c) * 16384 + m0 + mc * 8] = v;
        }
    } else {
        _Float16* dst = (z == 0) ? q : k;
        const int r0 = m0 + wr * 128 + gsel * 4;
        const int c0 = n0 + wc * 64 + rsel;
#pragma unroll
        for (int mI = 0; mI < 8; ++mI) {
#pragma unroll
            for (int nI = 0; nI < 4; ++nI) {
                const int r = r0 + mI * 16;
                const int c = c0 + nI * 16;
                const float bb = bias[c];
#pragma unroll
                for (int j = 0; j < 4; ++j)
                    dst[(long)(r + j) * 1024 + c] = (_Float16)(acc[mI][nI][j] + bb);
            }
        }
    }
}

// scores + partial softmax, spill-free epilogue (R12-verified).
__global__ __launch_bounds__(512, 2) void scores_kernel(const _Float16* qh,
                                                        const _Float16* kh,
                                                        _Float16* es, float* tmax,
                                                        float* tsum) {
    extern __shared__ _Float16 lds[];
    const int b = blockIdx.x;
    const int m0 = (blockIdx.y >> 3) * 256;
    const int tile = blockIdx.y & 7;
    const int n0 = tile * 256;
    floatx4 acc[8][4];
    zero_acc8(acc);
    gemm256_core(qh + ((long)b * 2048 + m0) * 1024, 1024,
                 kh + ((long)b * 2048 + n0) * 1024, 1024, 1024, acc, lds);

    const int lane = threadIdx.x & 63;
    const int w = threadIdx.x >> 6;
    const int wr = w >> 2, wc = w & 3;
    const int rsel = lane & 15, gsel = lane >> 4;
    const int tid = threadIdx.x;
    float* redp   = (float*)(lds + 32768);  // [256][68] fp32
    float* rowmax = (float*)(lds + 67584);  // [256] fp32
    const int slot = wc * 16 + rsel;

    // ---- P1: n-folded max partials -> redp[row][wc*16+rsel]
#pragma unroll
    for (int m = 0; m < 8; ++m) {
#pragma unroll
        for (int j = 0; j < 4; ++j) {
            const int row = wr * 128 + m * 16 + gsel * 4 + j;
            float v = acc[m][0][j];
#pragma unroll
            for (int n = 1; n < 4; ++n) v = fmaxf(v, acc[m][n][j]);
            redp[row * 68 + slot] = v;
        }
    }
    __syncthreads();

    // ---- P2: fold 64 partials/row -> rowmax (256 threads, float4 reads)
    if (tid < 256) {
        const float* rr = redp + tid * 68;
        float mv = -1e30f;
#pragma unroll
        for (int q4 = 0; q4 < 16; ++q4) {
            float4 f = ((const float4*)rr)[q4];
            mv = fmaxf(mv, fmaxf(fmaxf(f.x, f.y), fmaxf(f.z, f.w)));
        }
        rowmax[tid] = mv;
    }
    __syncthreads();

    // ---- P3: exp in regs, sum partials -> redp (reuse), esb half0 write
#pragma unroll
    for (int m = 0; m < 8; ++m) {
#pragma unroll
        for (int j = 0; j < 4; ++j) {
            const int row = wr * 128 + m * 16 + gsel * 4 + j;
            const float mxv = rowmax[row];
            float s = 0.f;
#pragma unroll
            for (int n = 0; n < 4; ++n) {
                float e = __expf(acc[m][n][j] - mxv);
                acc[m][n][j] = e;
                s += e;
            }
            redp[row * 68 + slot] = s;
        }
    }
#pragma unroll
    for (int m = 0; m < 4; ++m) {
#pragma unroll
        for (int j = 0; j < 4; ++j) {
            const int lr = wr * 64 + m * 16 + gsel * 4 + j;
            const int g = lr & 7;
#pragma unroll
            for (int n = 0; n < 4; ++n) {
                const int c = wc * 64 + n * 16 + rsel;
                lds[lr * 256 + (c ^ (g << 3))] = (_Float16)acc[m][n][j];
            }
        }
    }
    __syncthreads();

    // ---- P4: fold sum partials -> coalesced global tmax/tsum
    if (tid < 256) {
        const float* rr = redp + tid * 68;
        float sv = 0.f;
#pragma unroll
        for (int q4 = 0; q4 < 16; ++q4) {
            float4 f = ((const float4*)rr)[q4];
            sv += f.x + f.y + f.z + f.w;
        }
        const long base = ((long)b * 8 + tile) * 2048 + m0;
        tmax[base + tid] = rowmax[tid];
        tsum[base + tid] = sv;
    }
    // ---- P6a: vector readback + coalesced es store, half0 rows
    const long rbase = (long)b * 2048 * 2048;
#pragma unroll
    for (int it = 0; it < 8; ++it) {
        const int idx = it * 512 + tid;  // 0..4095
        const int lr = idx >> 5;         // 0..127
        const int chunk = idx & 31;
        half8 v = *(const half8*)&lds[lr * 256 + ((chunk ^ (lr & 7)) * 8)];
        const int rg = (lr & 63) + ((lr >> 6) << 7);  // rows 0-63,128-191
        *(half8*)&es[rbase + (long)(m0 + rg) * 2048 + n0 + chunk * 8] = v;
    }
    __syncthreads();

    // ---- P5b: esb half1 from acc m 4..7
#pragma unroll
    for (int m = 4; m < 8; ++m) {
#pragma unroll
        for (int j = 0; j < 4; ++j) {
            const int lr = wr * 64 + (m - 4) * 16 + gsel * 4 + j;
            const int g = lr & 7;
#pragma unroll
            for (int n = 0; n < 4; ++n) {
                const int c = wc * 64 + n * 16 + rsel;
                lds[lr * 256 + (c ^ (g << 3))] = (_Float16)acc[m][n][j];
            }
        }
    }
    __syncthreads();
    // ---- P6b: store half1 rows (64-127, 192-255)
#pragma unroll
    for (int it = 0; it < 8; ++it) {
        const int idx = it * 512 + tid;
        const int lr = idx >> 5;
        const int chunk = idx & 31;
        half8 v = *(const half8*)&lds[lr * 256 + ((chunk ^ (lr & 7)) * 8)];
        const int rg = 64 + (lr & 63) + ((lr >> 6) << 7);
        *(half8*)&es[rbase + (long)(m0 + rg) * 2048 + n0 + chunk * 8] = v;
    }
}

// weighted[b] = (es * scale)[b] @ v[b] via vT; scale computed in prologue.
__global__ __launch_bounds__(512, 2) void pv_kernel(const _Float16* es,
                                                    const _Float16* vT,
                                                    const float* tmax,
                                                    const float* tsum,
                                                    _Float16* wt) {
    extern __shared__ _Float16 lds[];
    const int batch = blockIdx.x;
    const int m0 = (blockIdx.y >> 2) * 256;
    const int n0 = (blockIdx.y & 3) * 256;
    float* scl = (float*)(lds + 65536);  // [8][256] after the 128KB dbuf
    if (threadIdx.x < 256) {
        const int row = m0 + threadIdx.x;
        float m[8];
        float mg = -1e30f;
#pragma unroll
        for (int t = 0; t < 8; ++t) {
            m[t] = tmax[((long)batch * 8 + t) * 2048 + row];
            mg = fmaxf(mg, m[t]);
        }
        float Z = 0.f;
#pragma unroll
        for (int t = 0; t < 8; ++t)
            Z += tsum[((long)batch * 8 + t) * 2048 + row] * __expf(m[t] - mg);
        const float inv = 1.0f / Z;
#pragma unroll
        for (int t = 0; t < 8; ++t)
            scl[t * 256 + threadIdx.x] = __expf(m[t] - mg) * inv;
    }
    __syncthreads();
    floatx4 acc[8][4];
    zero_acc8(acc);
    gemm256_core_pv(es + ((long)batch * 2048 + m0) * 2048, 2048,
                    vT + (long)n0 * 16384 + (long)batch * 2048, 16384, 2048, acc,
                    lds, scl);

    const int lane = threadIdx.x & 63;
    const int w = threadIdx.x >> 6;
    const int wr = w >> 2, wc = w & 3;
    const int r0 = wr * 128 + (lane >> 4) * 4;
    const int c0 = n0 + wc * 64 + (lane & 15);
#pragma unroll
    for (int m = 0; m < 8; ++m) {
#pragma unroll
        for (int n = 0; n < 4; ++n) {
            const int r = r0 + m * 16;
            const int c = c0 + n * 16;
#pragma unroll
            for (int j = 0; j < 4; ++j)
                wt[((long)batch * 2048 + m0 + r + j) * 1024 + c] =
                    (_Float16)acc[m][n][j];
        }
    }
}

// out = leakyrelu(weighted @ Wf^T + bf), fp32 out.
__global__ __launch_bounds__(512, 2) void out_kernel(const _Float16* wt, const _Float16* Wf,
                                                     const float* bf_, float* out) {
    extern __shared__ _Float16 lds[];
    const int m0 = blockIdx.x * 256;
    const int n0 = blockIdx.y * 256;
    floatx4 acc[8][4];
    zero_acc8(acc);
    gemm256_core(wt + (long)m0 * 1024, 1024, Wf + (long)n0 * 1024, 1024, 1024, acc, lds);

    const int lane = threadIdx.x & 63;
    const int w = threadIdx.x >> 6;
    const int wr = w >> 2, wc = w & 3;
    const int r0 = m0 + wr * 128 + (lane >> 4) * 4;
    const int c0 = n0 + wc * 64 + (lane & 15);
#pragma unroll
    for (int m = 0; m < 8; ++m) {
#pragma unroll
        for (int n = 0; n < 4; ++n) {
            const int r = r0 + m * 16;
            const int c = c0 + n * 16;
            const float bb = bf_[c];
#pragma unroll
            for (int j = 0; j < 4; ++j) {
                float y = acc[m][n][j] + bb;
                y = (y >= 0.f) ? y : 0.2f * y;
                out[(long)(r + j) * 1024 + c] = y;
            }
        }
    }
}

// ---------------- launcher ----------------
extern "C" void kernel_launch(void* const* d_in, const int* in_sizes, int n_in,
                              void* d_out, int out_size, void* d_ws, size_t ws_size,
                              hipStream_t stream) {
    const float* e1 = (const float*)d_in[0];
    const float* e2 = (const float*)d_in[1];
    const float* e3 = (const float*)d_in[2];
    const float* Wq = (const float*)d_in[3];
    const float* bq = (const float*)d_in[4];
    const float* Wk = (const float*)d_in[5];
    const float* bk = (const float*)d_in[6];
    const float* Wv = (const float*)d_in[7];
    const float* bv = (const float*)d_in[8];
    const float* Wf = (const float*)d_in[9];
    const float* bf_ = (const float*)d_in[10];
    float* out = (float*)d_out;

    const int LDS_BYTES = 131072;
    const int LDS_SC = 136192;
    const int LDS_PV = 131072 + 8192;
    (void)hipFuncSetAttribute((const void*)qkv_kernel,
                              hipFuncAttributeMaxDynamicSharedMemorySize, LDS_BYTES);
    (void)hipFuncSetAttribute((const void*)scores_kernel,
                              hipFuncAttributeMaxDynamicSharedMemorySize, LDS_SC);
    (void)hipFuncSetAttribute((const void*)pv_kernel,
                              hipFuncAttributeMaxDynamicSharedMemorySize, LDS_PV);
    (void)hipFuncSetAttribute((const void*)out_kernel,
                              hipFuncAttributeMaxDynamicSharedMemorySize, LDS_BYTES);

    char* ws = (char*)d_ws;
    const size_t MB = 1024 * 1024;
    _Float16* Xh    = (_Float16*)(ws + 0);        // 32 MiB
    _Float16* Wh    = (_Float16*)(ws + 32 * MB);  // 8 MiB
    _Float16* qh    = (_Float16*)(ws + 40 * MB);  // 32 MiB
    _Float16* kh    = (_Float16*)(ws + 72 * MB);  // 32 MiB
    _Float16* vT    = (_Float16*)(ws + 104 * MB); // 32 MiB [1024][16384]
    _Float16* wt    = (_Float16*)(ws + 136 * MB); // 32 MiB
    _Float16* es    = (_Float16*)(ws + 168 * MB); // 64 MiB [8][2048][2048] fp16
    float* tmax     = (float*)(ws + 232 * MB);              // 512 KiB [8][8][2048]
    float* tsum     = (float*)(ws + 232 * MB + 524288);     // 512 KiB

    prep_kernel<<<20480, 256, 0, stream>>>(e1, e2, e3, Wq, Wk, Wv, Wf, Xh, Wh);
    qkv_kernel<<<dim3(64, 4, 3), 512, LDS_BYTES, stream>>>(Xh, Wh, bq, bk, bv, qh, kh, vT);
    scores_kernel<<<dim3(8, 64), 512, LDS_SC, stream>>>(qh, kh, es, tmax, tsum);
    pv_kernel<<<dim3(8, 32), 512, LDS_PV, stream>>>(es, vT, tmax, tsum, wt);
    out_kernel<<<dim3(64, 4), 512, LDS_BYTES, stream>>>(wt, Wh + 3 * 1048576, bf_, out);
}

// Round 15
// 295.660 us; speedup vs baseline: 1.0402x; 1.0402x over previous
//
#include <hip/hip_runtime.h>
#include <hip/hip_fp16.h>

typedef _Float16 half8 __attribute__((ext_vector_type(8)));
typedef _Float16 half4v __attribute__((ext_vector_type(4)));
typedef float floatx4 __attribute__((ext_vector_type(4)));

// ---------------- async global->LDS (16B per lane) ----------------
__device__ __forceinline__ void load_lds16(const void* g, void* l) {
    __builtin_amdgcn_global_load_lds(
        (const __attribute__((address_space(1))) void*)g,
        (__attribute__((address_space(3))) void*)l,
        16, 0, 0);
}

// Stage one 128x64 fp16 half-tile (16 KiB) into LDS. LDS dest linear;
// SOURCE slot XOR-pre-swizzled (slot ^= row&7) -- Guideline 21.
__device__ __forceinline__ void stage_half(const _Float16* g, long ld, _Float16* dst) {
    const int t = threadIdx.x;  // 512 threads x 2 chunks x 16B
#pragma unroll
    for (int j = 0; j < 2; ++j) {
        const int c = j * 512 + t;             // 0..1023
        const int row = c >> 3;                // 0..127
        const int slot = (c & 7) ^ (row & 7);  // pre-swizzled source slot
        load_lds16(g + (long)row * ld + slot * 8, dst + c * 8);
    }
}

#define GEMM_PRELUDE                                                               \
    const int lane = threadIdx.x & 63;                                             \
    const int w    = threadIdx.x >> 6;                                             \
    const int wr   = w >> 2;                                                       \
    const int wc   = w & 3;                                                        \
    const int rsel = lane & 15, gsel = lane >> 4;                                  \
    const int NT = K >> 6;                                                         \
    (void)lane;
#define STAGE(BUF, KT)                                                             \
    stage_half(A + (KT) * 64, lda, lds + (BUF) * 32768);                           \
    stage_half(A + (long)128 * lda + (KT) * 64, lda, lds + (BUF) * 32768 + 8192);  \
    stage_half(B + (KT) * 64, ldb, lds + (BUF) * 32768 + 16384);                   \
    stage_half(B + (long)128 * ldb + (KT) * 64, ldb, lds + (BUF) * 32768 + 24576);
#define READ_A(dst, AH, MH)                                                        \
    _Pragma("unroll") for (int mi = 0; mi < 4; ++mi) {                             \
        const int r = ((MH) * 4 + mi) * 16 + rsel;                                 \
        dst[mi][0] = *(const half8*)&(AH)[r * 64 + ((gsel ^ (r & 7)) << 3)];       \
        dst[mi][1] = *(const half8*)&(AH)[r * 64 + (((4 + gsel) ^ (r & 7)) << 3)]; \
    }
#define READ_B(dst, BH, NH)                                                        \
    _Pragma("unroll") for (int ni = 0; ni < 2; ++ni) {                             \
        const int rn = (wc & 1) * 64 + ((NH) * 2 + ni) * 16 + rsel;                \
        dst[ni][0] = *(const half8*)&(BH)[rn * 64 + ((gsel ^ (rn & 7)) << 3)];     \
        dst[ni][1] = *(const half8*)&(BH)[rn * 64 + (((4 + gsel) ^ (rn & 7)) << 3)]; \
    }
#define MFMA_Q(MH, NH, A_, B_)                                                     \
    _Pragma("unroll") for (int mi = 0; mi < 4; ++mi)                               \
    _Pragma("unroll") for (int ni = 0; ni < 2; ++ni) {                             \
        acc[(MH) * 4 + mi][(NH) * 2 + ni] = __builtin_amdgcn_mfma_f32_16x16x32_f16( \
            A_[mi][0], B_[ni][0], acc[(MH) * 4 + mi][(NH) * 2 + ni], 0, 0, 0);     \
        acc[(MH) * 4 + mi][(NH) * 2 + ni] = __builtin_amdgcn_mfma_f32_16x16x32_f16( \
            A_[mi][1], B_[ni][1], acc[(MH) * 4 + mi][(NH) * 2 + ni], 0, 0, 0);     \
    }
#define SB0 __builtin_amdgcn_sched_barrier(0)

// ---------------- 256x256 gemm_bt core (R7-verified, 42% MfmaUtil) ----------
// One barrier + counted lgkmcnt per K-tile; stage(t+1) issued before the
// tile's reads; vmcnt(0) drained at tile end. Schedule is the measured local
// optimum (8-phase falsified 3x: R3/R4/R13; setprio/mid-drain hurt: R6).
__device__ __forceinline__ void gemm256_core(const _Float16* A, long lda,
                                             const _Float16* B, long ldb,
                                             int K, floatx4 acc[8][4],
                                             _Float16* lds) {
    GEMM_PRELUDE
    half8 a_lo[4][2], a_hi[4][2], b_lo[2][2], b_hi[2][2];
    STAGE(0, 0);
    asm volatile("s_waitcnt vmcnt(0)" ::: "memory");
    __builtin_amdgcn_s_barrier();
    SB0;
#pragma unroll 1
    for (int t = 0; t < NT; ++t) {
        const int buf = t & 1;
        if (t + 1 < NT) { STAGE(buf ^ 1, t + 1); }
        const _Float16* Ah = lds + buf * 32768 + wr * 8192;
        const _Float16* Bh = lds + buf * 32768 + 16384 + (wc >> 1) * 8192;
        READ_A(a_lo, Ah, 0);
        READ_B(b_lo, Bh, 0);
        SB0;
        READ_A(a_hi, Ah, 1);
        SB0;
        READ_B(b_hi, Bh, 1);
        asm volatile("s_waitcnt lgkmcnt(12)" ::: "memory");
        SB0;
        MFMA_Q(0, 0, a_lo, b_lo);
        asm volatile("s_waitcnt lgkmcnt(4)" ::: "memory");
        SB0;
        MFMA_Q(1, 0, a_hi, b_lo);
        asm volatile("s_waitcnt lgkmcnt(0)" ::: "memory");
        SB0;
        MFMA_Q(0, 1, a_lo, b_hi);
        MFMA_Q(1, 1, a_hi, b_hi);
        asm volatile("s_waitcnt vmcnt(0)" ::: "memory");
        __builtin_amdgcn_s_barrier();
        SB0;
    }
}

// ---------------- pv variant: per-row fp16 A-scaling from LDS table --------
__device__ __forceinline__ void gemm256_core_pv(const _Float16* A, long lda,
                                                const _Float16* B, long ldb,
                                                int K, floatx4 acc[8][4],
                                                _Float16* lds, const float* scl) {
    GEMM_PRELUDE
    half8 a_lo[4][2], a_hi[4][2], b_lo[2][2], b_hi[2][2];
    STAGE(0, 0);
    asm volatile("s_waitcnt vmcnt(0)" ::: "memory");
    __builtin_amdgcn_s_barrier();
    SB0;
#pragma unroll 1
    for (int t = 0; t < NT; ++t) {
        const int buf = t & 1;
        if (t + 1 < NT) { STAGE(buf ^ 1, t + 1); }
        const _Float16* Ah = lds + buf * 32768 + wr * 8192;
        const _Float16* Bh = lds + buf * 32768 + 16384 + (wc >> 1) * 8192;
        const float* srow = scl + (t >> 2) * 256 + wr * 128 + rsel;
        float s_lo[4], s_hi[4];
#pragma unroll
        for (int mi = 0; mi < 4; ++mi) s_lo[mi] = srow[mi * 16];
#pragma unroll
        for (int mi = 0; mi < 4; ++mi) s_hi[mi] = srow[64 + mi * 16];
        SB0;
        READ_A(a_lo, Ah, 0);
        READ_B(b_lo, Bh, 0);
        SB0;
        READ_A(a_hi, Ah, 1);
        SB0;
        READ_B(b_hi, Bh, 1);
        asm volatile("s_waitcnt lgkmcnt(12)" ::: "memory");
        SB0;
#pragma unroll
        for (int mi = 0; mi < 4; ++mi) {
            const _Float16 h = (_Float16)s_lo[mi];
            a_lo[mi][0] = a_lo[mi][0] * h;
            a_lo[mi][1] = a_lo[mi][1] * h;
        }
        MFMA_Q(0, 0, a_lo, b_lo);
        asm volatile("s_waitcnt lgkmcnt(4)" ::: "memory");
        SB0;
#pragma unroll
        for (int mi = 0; mi < 4; ++mi) {
            const _Float16 h = (_Float16)s_hi[mi];
            a_hi[mi][0] = a_hi[mi][0] * h;
            a_hi[mi][1] = a_hi[mi][1] * h;
        }
        MFMA_Q(1, 0, a_hi, b_lo);
        asm volatile("s_waitcnt lgkmcnt(0)" ::: "memory");
        SB0;
        MFMA_Q(0, 1, a_lo, b_hi);
        MFMA_Q(1, 1, a_hi, b_hi);
        asm volatile("s_waitcnt vmcnt(0)" ::: "memory");
        __builtin_amdgcn_s_barrier();
        SB0;
    }
}

__device__ __forceinline__ void zero_acc8(floatx4 acc[8][4]) {
    const floatx4 z = {0.f, 0.f, 0.f, 0.f};
#pragma unroll
    for (int m = 0; m < 8; ++m)
#pragma unroll
        for (int n = 0; n < 4; ++n) acc[m][n] = z;
}

// ---------------- kernels ----------------

// merged prep: blocks [0,16384) build X fp16; [16384,20480) convert weights.
__global__ __launch_bounds__(256) void prep_kernel(const float* e1, const float* e2,
                                                   const float* e3, const float* Wq,
                                                   const float* Wk, const float* Wv,
                                                   const float* Wf, _Float16* X,
                                                   _Float16* Wdst) {
    const int bid = blockIdx.x;
    if (bid < 16384) {
        long i = ((long)bid * 256 + threadIdx.x) * 4;
        int m = (int)(i >> 10);
        int c = (int)(i & 1023);
        const float* src;
        if (c < 256)      src = e1 + (long)m * 256 + c;
        else if (c < 512) src = e2 + (long)m * 256 + (c - 256);
        else              src = e3 + (long)m * 512 + (c - 512);
        float4 f = *(const float4*)src;
        half4v h;
        h[0] = (_Float16)f.x; h[1] = (_Float16)f.y;
        h[2] = (_Float16)f.z; h[3] = (_Float16)f.w;
        *(half4v*)&X[i] = h;
    } else {
        long i = ((long)(bid - 16384) * 256 + threadIdx.x) * 4;
        int which = (int)(i >> 20);
        long off = i & 1048575;
        const float* w = which == 0 ? Wq : which == 1 ? Wk : which == 2 ? Wv : Wf;
        float4 f = *(const float4*)(w + off);
        half4v h;
        h[0] = (_Float16)f.x; h[1] = (_Float16)f.y;
        h[2] = (_Float16)f.z; h[3] = (_Float16)f.w;
        *(half4v*)&Wdst[i] = h;
    }
}

// QKV projection: z=0 -> q, z=1 -> k; z=2 -> vT via LDS transpose.
__global__ __launch_bounds__(512, 2) void qkv_kernel(const _Float16* X, const _Float16* W,
                                                     const float* bq, const float* bk,
                                                     const float* bv, _Float16* q,
                                                     _Float16* k, _Float16* vT) {
    extern __shared__ _Float16 lds[];
    const int m0 = blockIdx.x * 256;
    const int n0 = blockIdx.y * 256;
    const int z  = blockIdx.z;
    floatx4 acc[8][4];
    zero_acc8(acc);
    gemm256_core(X + (long)m0 * 1024, 1024,
                 W + (long)z * 1048576 + (long)n0 * 1024, 1024, 1024, acc, lds);

    const float* bias = (z == 0) ? bq : (z == 1) ? bk : bv;
    const int lane = threadIdx.x & 63;
    const int w = threadIdx.x >> 6;
    const int wr = w >> 2, wc = w & 3;
    const int rsel = lane & 15, gsel = lane >> 4;

    if (z == 2) {
        const int rb = wr * 128 + gsel * 4;
        const int cb = wc * 64 + rsel;
#pragma unroll
        for (int mI = 0; mI < 8; ++mI) {
#pragma unroll
            for (int nI = 0; nI < 4; ++nI) {
                const int c = cb + nI * 16;
                const int r = rb + mI * 16;
                const float bb = bias[n0 + c];
                half4v vv;
#pragma unroll
                for (int j = 0; j < 4; ++j) vv[j] = (_Float16)(acc[mI][nI][j] + bb);
                *(half4v*)&lds[c * 256 + (r ^ ((c & 7) << 3))] = vv;
            }
        }
        __syncthreads();
#pragma unroll
        for (int it = 0; it < 16; ++it) {
            const int idx = it * 512 + threadIdx.x;  // 0..8191
            const int c = idx >> 5;
            const int mc = idx & 31;
            half8 v = *(const half8*)&lds[c * 256 + ((mc * 8) ^ ((c & 7) << 3))];
            *(half8*)&vT[(long)(n0 + c) * 16384 + m0 + mc * 8] = v;
        }
    } else {
        _Float16* dst = (z == 0) ? q : k;
        const int r0 = m0 + wr * 128 + gsel * 4;
        const int c0 = n0 + wc * 64 + rsel;
#pragma unroll
        for (int mI = 0; mI < 8; ++mI) {
#pragma unroll
            for (int nI = 0; nI < 4; ++nI) {
                const int r = r0 + mI * 16;
                const int c = c0 + nI * 16;
                const float bb = bias[c];
#pragma unroll
                for (int j = 0; j < 4; ++j)
                    dst[(long)(r + j) * 1024 + c] = (_Float16)(acc[mI][nI][j] + bb);
            }
        }
    }
}

// scores + partial softmax, spill-free epilogue (R12-verified).
__global__ __launch_bounds__(512, 2) void scores_kernel(const _Float16* qh,
                                                        const _Float16* kh,
                                                        _Float16* es, float* tmax,
                                                        float* tsum) {
    extern __shared__ _Float16 lds[];
    const int b = blockIdx.x;
    const int m0 = (blockIdx.y >> 3) * 256;
    const int tile = blockIdx.y & 7;
    const int n0 = tile * 256;
    floatx4 acc[8][4];
    zero_acc8(acc);
    gemm256_core(qh + ((long)b * 2048 + m0) * 1024, 1024,
                 kh + ((long)b * 2048 + n0) * 1024, 1024, 1024, acc, lds);

    const int lane = threadIdx.x & 63;
    const int w = threadIdx.x >> 6;
    const int wr = w >> 2, wc = w & 3;
    const int rsel = lane & 15, gsel = lane >> 4;
    const int tid = threadIdx.x;
    float* redp   = (float*)(lds + 32768);  // [256][68] fp32
    float* rowmax = (float*)(lds + 67584);  // [256] fp32
    const int slot = wc * 16 + rsel;

    // ---- P1: n-folded max partials -> redp[row][wc*16+rsel]
#pragma unroll
    for (int m = 0; m < 8; ++m) {
#pragma unroll
        for (int j = 0; j < 4; ++j) {
            const int row = wr * 128 + m * 16 + gsel * 4 + j;
            float v = acc[m][0][j];
#pragma unroll
            for (int n = 1; n < 4; ++n) v = fmaxf(v, acc[m][n][j]);
            redp[row * 68 + slot] = v;
        }
    }
    __syncthreads();

    // ---- P2: fold 64 partials/row -> rowmax (256 threads, float4 reads)
    if (tid < 256) {
        const float* rr = redp + tid * 68;
        float mv = -1e30f;
#pragma unroll
        for (int q4 = 0; q4 < 16; ++q4) {
            float4 f = ((const float4*)rr)[q4];
            mv = fmaxf(mv, fmaxf(fmaxf(f.x, f.y), fmaxf(f.z, f.w)));
        }
        rowmax[tid] = mv;
    }
    __syncthreads();

    // ---- P3: exp in regs, sum partials -> redp (reuse), esb half0 write
#pragma unroll
    for (int m = 0; m < 8; ++m) {
#pragma unroll
        for (int j = 0; j < 4; ++j) {
            const int row = wr * 128 + m * 16 + gsel * 4 + j;
            const float mxv = rowmax[row];
            float s = 0.f;
#pragma unroll
            for (int n = 0; n < 4; ++n) {
                float e = __expf(acc[m][n][j] - mxv);
                acc[m][n][j] = e;
                s += e;
            }
            redp[row * 68 + slot] = s;
        }
    }
#pragma unroll
    for (int m = 0; m < 4; ++m) {
#pragma unroll
        for (int j = 0; j < 4; ++j) {
            const int lr = wr * 64 + m * 16 + gsel * 4 + j;
            const int g = lr & 7;
#pragma unroll
            for (int n = 0; n < 4; ++n) {
                const int c = wc * 64 + n * 16 + rsel;
                lds[lr * 256 + (c ^ (g << 3))] = (_Float16)acc[m][n][j];
            }
        }
    }
    __syncthreads();

    // ---- P4: fold sum partials -> coalesced global tmax/tsum
    if (tid < 256) {
        const float* rr = redp + tid * 68;
        float sv = 0.f;
#pragma unroll
        for (int q4 = 0; q4 < 16; ++q4) {
            float4 f = ((const float4*)rr)[q4];
            sv += f.x + f.y + f.z + f.w;
        }
        const long base = ((long)b * 8 + tile) * 2048 + m0;
        tmax[base + tid] = rowmax[tid];
        tsum[base + tid] = sv;
    }
    // ---- P6a: vector readback + coalesced es store, half0 rows
    const long rbase = (long)b * 2048 * 2048;
#pragma unroll
    for (int it = 0; it < 8; ++it) {
        const int idx = it * 512 + tid;  // 0..4095
        const int lr = idx >> 5;         // 0..127
        const int chunk = idx & 31;
        half8 v = *(const half8*)&lds[lr * 256 + ((chunk ^ (lr & 7)) * 8)];
        const int rg = (lr & 63) + ((lr >> 6) << 7);  // rows 0-63,128-191
        *(half8*)&es[rbase + (long)(m0 + rg) * 2048 + n0 + chunk * 8] = v;
    }
    __syncthreads();

    // ---- P5b: esb half1 from acc m 4..7
#pragma unroll
    for (int m = 4; m < 8; ++m) {
#pragma unroll
        for (int j = 0; j < 4; ++j) {
            const int lr = wr * 64 + (m - 4) * 16 + gsel * 4 + j;
            const int g = lr & 7;
#pragma unroll
            for (int n = 0; n < 4; ++n) {
                const int c = wc * 64 + n * 16 + rsel;
                lds[lr * 256 + (c ^ (g << 3))] = (_Float16)acc[m][n][j];
            }
        }
    }
    __syncthreads();
    // ---- P6b: store half1 rows (64-127, 192-255)
#pragma unroll
    for (int it = 0; it < 8; ++it) {
        const int idx = it * 512 + tid;
        const int lr = idx >> 5;
        const int chunk = idx & 31;
        half8 v = *(const half8*)&lds[lr * 256 + ((chunk ^ (lr & 7)) * 8)];
        const int rg = 64 + (lr & 63) + ((lr >> 6) << 7);
        *(half8*)&es[rbase + (long)(m0 + rg) * 2048 + n0 + chunk * 8] = v;
    }
}

// weighted[b] = (es * scale)[b] @ v[b] via vT; scale computed in prologue.
__global__ __launch_bounds__(512, 2) void pv_kernel(const _Float16* es,
                                                    const _Float16* vT,
                                                    const float* tmax,
                                                    const float* tsum,
                                                    _Float16* wt) {
    extern __shared__ _Float16 lds[];
    const int batch = blockIdx.x;
    const int m0 = (blockIdx.y >> 2) * 256;
    const int n0 = (blockIdx.y & 3) * 256;
    float* scl = (float*)(lds + 65536);  // [8][256] after the 128KB dbuf
    if (threadIdx.x < 256) {
        const int row = m0 + threadIdx.x;
        float m[8];
        float mg = -1e30f;
#pragma unroll
        for (int t = 0; t < 8; ++t) {
            m[t] = tmax[((long)batch * 8 + t) * 2048 + row];
            mg = fmaxf(mg, m[t]);
        }
        float Z = 0.f;
#pragma unroll
        for (int t = 0; t < 8; ++t)
            Z += tsum[((long)batch * 8 + t) * 2048 + row] * __expf(m[t] - mg);
        const float inv = 1.0f / Z;
#pragma unroll
        for (int t = 0; t < 8; ++t)
            scl[t * 256 + threadIdx.x] = __expf(m[t] - mg) * inv;
    }
    __syncthreads();
    floatx4 acc[8][4];
    zero_acc8(acc);
    gemm256_core_pv(es + ((long)batch * 2048 + m0) * 2048, 2048,
                    vT + (long)n0 * 16384 + (long)batch * 2048, 16384, 2048, acc,
                    lds, scl);

    const int lane = threadIdx.x & 63;
    const int w = threadIdx.x >> 6;
    const int wr = w >> 2, wc = w & 3;
    const int r0 = wr * 128 + (lane >> 4) * 4;
    const int c0 = n0 + wc * 64 + (lane & 15);
#pragma unroll
    for (int m = 0; m < 8; ++m) {
#pragma unroll
        for (int n = 0; n < 4; ++n) {
            const int r = r0 + m * 16;
            const int c = c0 + n * 16;
#pragma unroll
            for (int j = 0; j < 4; ++j)
                wt[((long)batch * 2048 + m0 + r + j) * 1024 + c] =
                    (_Float16)acc[m][n][j];
        }
    }
}

// out = leakyrelu(weighted @ Wf^T + bf), fp32 out.
__global__ __launch_bounds__(512, 2) void out_kernel(const _Float16* wt, const _Float16* Wf,
                                                     const float* bf_, float* out) {
    extern __shared__ _Float16 lds[];
    const int m0 = blockIdx.x * 256;
    const int n0 = blockIdx.y * 256;
    floatx4 acc[8][4];
    zero_acc8(acc);
    gemm256_core(wt + (long)m0 * 1024, 1024, Wf + (long)n0 * 1024, 1024, 1024, acc, lds);

    const int lane = threadIdx.x & 63;
    const int w = threadIdx.x >> 6;
    const int wr = w >> 2, wc = w & 3;
    const int r0 = m0 + wr * 128 + (lane >> 4) * 4;
    const int c0 = n0 + wc * 64 + (lane & 15);
#pragma unroll
    for (int m = 0; m < 8; ++m) {
#pragma unroll
        for (int n = 0; n < 4; ++n) {
            const int r = r0 + m * 16;
            const int c = c0 + n * 16;
            const float bb = bf_[c];
#pragma unroll
            for (int j = 0; j < 4; ++j) {
                float y = acc[m][n][j] + bb;
                y = (y >= 0.f) ? y : 0.2f * y;
                out[(long)(r + j) * 1024 + c] = y;
            }
        }
    }
}

// ---------------- launcher ----------------
extern "C" void kernel_launch(void* const* d_in, const int* in_sizes, int n_in,
                              void* d_out, int out_size, void* d_ws, size_t ws_size,
                              hipStream_t stream) {
    const float* e1 = (const float*)d_in[0];
    const float* e2 = (const float*)d_in[1];
    const float* e3 = (const float*)d_in[2];
    const float* Wq = (const float*)d_in[3];
    const float* bq = (const float*)d_in[4];
    const float* Wk = (const float*)d_in[5];
    const float* bk = (const float*)d_in[6];
    const float* Wv = (const float*)d_in[7];
    const float* bv = (const float*)d_in[8];
    const float* Wf = (const float*)d_in[9];
    const float* bf_ = (const float*)d_in[10];
    float* out = (float*)d_out;

    const int LDS_BYTES = 131072;
    const int LDS_SC = 136192;
    const int LDS_PV = 131072 + 8192;
    (void)hipFuncSetAttribute((const void*)qkv_kernel,
                              hipFuncAttributeMaxDynamicSharedMemorySize, LDS_BYTES);
    (void)hipFuncSetAttribute((const void*)scores_kernel,
                              hipFuncAttributeMaxDynamicSharedMemorySize, LDS_SC);
    (void)hipFuncSetAttribute((const void*)pv_kernel,
                              hipFuncAttributeMaxDynamicSharedMemorySize, LDS_PV);
    (void)hipFuncSetAttribute((const void*)out_kernel,
                              hipFuncAttributeMaxDynamicSharedMemorySize, LDS_BYTES);

    char* ws = (char*)d_ws;
    const size_t MB = 1024 * 1024;
    _Float16* Xh    = (_Float16*)(ws + 0);        // 32 MiB
    _Float16* Wh    = (_Float16*)(ws + 32 * MB);  // 8 MiB
    _Float16* qh    = (_Float16*)(ws + 40 * MB);  // 32 MiB
    _Float16* kh    = (_Float16*)(ws + 72 * MB);  // 32 MiB
    _Float16* vT    = (_Float16*)(ws + 104 * MB); // 32 MiB [1024][16384]
    _Float16* wt    = (_Float16*)(ws + 136 * MB); // 32 MiB
    _Float16* es    = (_Float16*)(ws + 168 * MB); // 64 MiB [8][2048][2048] fp16
    float* tmax     = (float*)(ws + 232 * MB);              // 512 KiB [8][8][2048]
    float* tsum     = (float*)(ws + 232 * MB + 524288);     // 512 KiB

    prep_kernel<<<20480, 256, 0, stream>>>(e1, e2, e3, Wq, Wk, Wv, Wf, Xh, Wh);
    qkv_kernel<<<dim3(64, 4, 3), 512, LDS_BYTES, stream>>>(Xh, Wh, bq, bk, bv, qh, kh, vT);
    scores_kernel<<<dim3(8, 64), 512, LDS_SC, stream>>>(qh, kh, es, tmax, tsum);
    pv_kernel<<<dim3(8, 32), 512, LDS_PV, stream>>>(es, vT, tmax, tsum, wt);
    out_kernel<<<dim3(64, 4), 512, LDS_BYTES, stream>>>(wt, Wh + 3 * 1048576, bf_, out);
}